// Round 2
// baseline (145686.987 us; speedup 1.0000x reference)
//
#include <hip/hip_runtime.h>
#include <hip/hip_bf16.h>

typedef unsigned short u16;
typedef unsigned int u32;

// ---------- sizes ----------
#define T_  8192
#define F_  1024
#define H_  2048
#define G_  8192   // 4*H

// ws layout (bytes). Total ~243.3 MB — assumes ws_size >= 244 MB.
#define WS_XG    0                    // bf16 [T][G]          134217728
#define WS_ABF   134217728ull         // bf16 [T][F]           16777216
#define WS_WBF   150994944ull         // bf16 [G][F]           16777216
#define WS_HH    167772160ull         // f32  [T+1][H]         67117056
#define WS_PART  234889216ull         // f32  [T][256]          8388608
#define WS_CNT   243277824ull         // u32 counter

static __device__ __forceinline__ float bf2f(u16 u) {
    union { u32 i; float f; } x; x.i = ((u32)u) << 16; return x.f;
}
static __device__ __forceinline__ u16 f2bf(float f) {
    union { float f; u32 u; } x; x.f = f;
    u32 r = (x.u + 0x7fffu + ((x.u >> 16) & 1u)) >> 16;
    return (u16)r;
}

// ---------- fp32 -> bf16 convert (4 elems/thread) ----------
__global__ void cvt4_kernel(const float* __restrict__ s, u16* __restrict__ d, int n4) {
    int i = blockIdx.x * 256 + threadIdx.x;
    if (i < n4) {
        float4 v = ((const float4*)s)[i];
        union { u16 h[4]; uint2 v2; } o;
        o.h[0] = f2bf(v.x); o.h[1] = f2bf(v.y); o.h[2] = f2bf(v.z); o.h[3] = f2bf(v.w);
        ((uint2*)d)[i] = o.v2;
    }
}

// ---------- x_gates GEMM: xg[t][g] = sum_f A[t][f]*W[g][f] + b_ih[g]+b_hh[g] ----------
// block 256 thr (4 waves), tile 64(t) x 64(g), K-step 32, bf16 MFMA 16x16x32.
__global__ __launch_bounds__(256) void gemm_xg_kernel(
    const u16* __restrict__ A,   // [T][F] bf16
    const u16* __restrict__ W,   // [G][F] bf16
    const float* __restrict__ b_ih, const float* __restrict__ b_hh,
    u16* __restrict__ xg)        // [T][G] bf16
{
    __shared__ u16 As[64][40];   // +8 pad (keeps 16B-aligned stores, breaks conflicts)
    __shared__ u16 Ws[64][40];

    const int tb = blockIdx.y * 64;
    const int gb = blockIdx.x * 64;
    const int tid  = threadIdx.x;
    const int wave = tid >> 6;       // 0..3 -> g sub-tile
    const int lane = tid & 63;
    const int m    = lane & 15;
    const int quad = lane >> 4;

    const int lrow = tid >> 2;        // 0..63
    const int lcol = (tid & 3) * 8;   // 0,8,16,24

    using frag  = __attribute__((ext_vector_type(8))) short;
    using f32x4 = __attribute__((ext_vector_type(4))) float;
    f32x4 acc[4] = {};  // 4 t-subtiles of 16x16

    for (int k0 = 0; k0 < F_; k0 += 32) {
        __syncthreads();
        *(uint4*)&As[lrow][lcol] = *(const uint4*)&A[(size_t)(tb + lrow) * F_ + k0 + lcol];
        *(uint4*)&Ws[lrow][lcol] = *(const uint4*)&W[(size_t)(gb + lrow) * F_ + k0 + lcol];
        __syncthreads();
        frag bfr = *(const frag*)&Ws[wave * 16 + m][quad * 8];
#pragma unroll
        for (int i = 0; i < 4; ++i) {
            frag afr = *(const frag*)&As[i * 16 + m][quad * 8];
            acc[i] = __builtin_amdgcn_mfma_f32_16x16x32_bf16(afr, bfr, acc[i], 0, 0, 0);
        }
    }
    // C[row=(quad*4+r)+16i (t), col=m (g)]
    const int g = gb + wave * 16 + m;
    const float bias = b_ih[g] + b_hh[g];
#pragma unroll
    for (int i = 0; i < 4; ++i)
#pragma unroll
        for (int r = 0; r < 4; ++r) {
            int t = tb + i * 16 + quad * 4 + r;
            xg[(size_t)t * G_ + g] = f2bf(acc[i][r] + bias);
        }
}

// ---------- persistent LSTM recurrence ----------
// 256 blocks x 512 threads (8 waves). Wave w of block b owns hidden unit uu=b*8+w:
// its 4 gate rows of W_hh live in registers (4 rows x 32 cols/lane = 128 VGPRs).
// Per step: LDS-broadcast h, 128 FMAs/lane, 64-lane butterfly, lane0 does the
// cell update, global h write + agent-scope barrier, reload h.
__global__ __launch_bounds__(512, 2) void lstm_rec_kernel(
    const float* __restrict__ Whh,   // [G][H] f32
    const u16*  __restrict__ xg,     // [T][G] bf16
    const float* __restrict__ Wout,  // [H]
    float* __restrict__ hh,          // [T+1][H]; slot 0 pre-zeroed
    float* __restrict__ part,        // [T][256]
    u32*   __restrict__ cnt)         // pre-zeroed
{
    __shared__ float hs[H_];
    __shared__ float pl[8];

    const int b   = blockIdx.x;
    const int tid = threadIdx.x;
    const int w   = tid >> 6;
    const int l   = tid & 63;
    const int uu  = b * 8 + w;          // hidden unit (wave-uniform)

    // preload weights: wreg[r][kc*4+j] = Whh[2048*r + uu][4*l + 256*kc + j]
    float wreg[4][32];
#pragma unroll
    for (int r = 0; r < 4; ++r) {
        const float* wrow = &Whh[(size_t)(2048 * r + uu) * H_];
#pragma unroll
        for (int kc = 0; kc < 8; ++kc) {
            float4 v = *(const float4*)&wrow[4 * l + 256 * kc];
            wreg[r][kc * 4 + 0] = v.x; wreg[r][kc * 4 + 1] = v.y;
            wreg[r][kc * 4 + 2] = v.z; wreg[r][kc * 4 + 3] = v.w;
        }
    }
    const float wout = Wout[uu];
    float c = 0.f;

    // h_{-1} = 0 from slot 0
    *(float4*)&hs[tid * 4] = *(const float4*)&hh[tid * 4];
    __syncthreads();

    for (int t = 0; t < T_; ++t) {
        // prefetch this step's x-gate contributions (lane 0 only uses them)
        float xgi = 0.f, xgf = 0.f, xgg = 0.f, xgo = 0.f;
        if (l == 0) {
            const u16* xr = &xg[(size_t)t * G_ + uu];
            xgi = bf2f(xr[0]); xgf = bf2f(xr[2048]);
            xgg = bf2f(xr[4096]); xgo = bf2f(xr[6144]);
        }

        float a0 = 0.f, a1 = 0.f, a2 = 0.f, a3 = 0.f;
#pragma unroll
        for (int kc = 0; kc < 8; ++kc) {
            float4 hv = *(const float4*)&hs[4 * l + 256 * kc];
            a0 = fmaf(wreg[0][kc*4+0], hv.x, a0); a0 = fmaf(wreg[0][kc*4+1], hv.y, a0);
            a0 = fmaf(wreg[0][kc*4+2], hv.z, a0); a0 = fmaf(wreg[0][kc*4+3], hv.w, a0);
            a1 = fmaf(wreg[1][kc*4+0], hv.x, a1); a1 = fmaf(wreg[1][kc*4+1], hv.y, a1);
            a1 = fmaf(wreg[1][kc*4+2], hv.z, a1); a1 = fmaf(wreg[1][kc*4+3], hv.w, a1);
            a2 = fmaf(wreg[2][kc*4+0], hv.x, a2); a2 = fmaf(wreg[2][kc*4+1], hv.y, a2);
            a2 = fmaf(wreg[2][kc*4+2], hv.z, a2); a2 = fmaf(wreg[2][kc*4+3], hv.w, a2);
            a3 = fmaf(wreg[3][kc*4+0], hv.x, a3); a3 = fmaf(wreg[3][kc*4+1], hv.y, a3);
            a3 = fmaf(wreg[3][kc*4+2], hv.z, a3); a3 = fmaf(wreg[3][kc*4+3], hv.w, a3);
        }
#pragma unroll
        for (int off = 32; off >= 1; off >>= 1) {
            a0 += __shfl_down(a0, off);
            a1 += __shfl_down(a1, off);
            a2 += __shfl_down(a2, off);
            a3 += __shfl_down(a3, off);
        }

        if (l == 0) {
            float gi = a0 + xgi, gf = a1 + xgf, gg = a2 + xgg, go = a3 + xgo;
            float i_ = 1.f / (1.f + __expf(-gi));
            float f_ = 1.f / (1.f + __expf(-gf));
            float g_ = tanhf(gg);
            float o_ = 1.f / (1.f + __expf(-go));
            c = fmaf(f_, c, i_ * g_);
            float hval = o_ * tanhf(c);
            hh[(size_t)(t + 1) * H_ + uu] = hval;
            pl[w] = hval * wout;
        }
        __syncthreads();   // all waves' h stores drained (vmcnt(0) before s_barrier)

        if (tid == 0) {
            part[(size_t)t * 256 + b] = pl[0] + pl[1] + pl[2] + pl[3]
                                      + pl[4] + pl[5] + pl[6] + pl[7];
            __threadfence();  // release: h store + part store visible device-wide
            __hip_atomic_fetch_add(cnt, 1u, __ATOMIC_RELAXED, __HIP_MEMORY_SCOPE_AGENT);
            const u32 target = (u32)(t + 1) * 256u;
            while (__hip_atomic_load(cnt, __ATOMIC_RELAXED, __HIP_MEMORY_SCOPE_AGENT) < target) { }
            __threadfence();  // acquire: invalidate caches before reading other blocks' h
        }
        __syncthreads();

        // broadcast h_t into LDS for next step (fresh addresses; caches invalidated)
        *(float4*)&hs[tid * 4] = *(const float4*)&hh[(size_t)(t + 1) * H_ + tid * 4];
        __syncthreads();
    }
}

// ---------- final: out[t] = b_out + sum_b part[t][b] ----------
__global__ __launch_bounds__(256) void out_reduce_kernel(
    const float* __restrict__ part, const float* __restrict__ b_out,
    float* __restrict__ out)
{
    int t = blockIdx.x * 4 + (threadIdx.x >> 6);
    int l = threadIdx.x & 63;
    const float* p = &part[(size_t)t * 256];
    float s = p[l] + p[l + 64] + p[l + 128] + p[l + 192];
#pragma unroll
    for (int off = 32; off >= 1; off >>= 1) s += __shfl_down(s, off);
    if (l == 0) out[t] = s + b_out[0];
}

extern "C" void kernel_launch(void* const* d_in, const int* in_sizes, int n_in,
                              void* d_out, int out_size, void* d_ws, size_t ws_size,
                              hipStream_t stream) {
    const float* input = (const float*)d_in[0];
    const float* W_ih  = (const float*)d_in[1];
    const float* W_hh  = (const float*)d_in[2];
    const float* b_ih  = (const float*)d_in[3];
    const float* b_hh  = (const float*)d_in[4];
    const float* W_out = (const float*)d_in[5];
    const float* b_out = (const float*)d_in[6];
    float* out = (float*)d_out;

    char* ws = (char*)d_ws;
    u16*   xg   = (u16*)(ws + WS_XG);
    u16*   Abf  = (u16*)(ws + WS_ABF);
    u16*   Wbf  = (u16*)(ws + WS_WBF);
    float* hh   = (float*)(ws + WS_HH);
    float* part = (float*)(ws + WS_PART);
    u32*   cnt  = (u32*)(ws + WS_CNT);

    // zero h_{-1} slot and the barrier counter (ws is poisoned 0xAA each run)
    (void)hipMemsetAsync(hh, 0, H_ * sizeof(float), stream);
    (void)hipMemsetAsync(cnt, 0, sizeof(u32), stream);

    const int n4 = (T_ * F_) / 4;  // 2097152 for both input and W_ih
    cvt4_kernel<<<(n4 + 255) / 256, 256, 0, stream>>>(input, Abf, n4);
    cvt4_kernel<<<(G_ * F_ / 4 + 255) / 256, 256, 0, stream>>>(W_ih, Wbf, G_ * F_ / 4);

    gemm_xg_kernel<<<dim3(G_ / 64, T_ / 64), 256, 0, stream>>>(Abf, Wbf, b_ih, b_hh, xg);

    lstm_rec_kernel<<<256, 512, 0, stream>>>(W_hh, xg, W_out, hh, part, cnt);

    out_reduce_kernel<<<T_ / 4, 256, 0, stream>>>(part, b_out, out);
}

// Round 3
// 42505.637 us; speedup vs baseline: 3.4275x; 3.4275x over previous
//
#include <hip/hip_runtime.h>
#include <hip/hip_bf16.h>

typedef unsigned short u16;
typedef unsigned int u32;
typedef unsigned long long u64;

// ---------- sizes ----------
#define T_  8192
#define F_  1024
#define H_  2048
#define G_  8192   // 4*H

// ws layout (bytes). Total ~243.3 MB — assumes ws_size >= 244 MB.
#define WS_XG    0                    // bf16 [T][G]          134217728
#define WS_ABF   134217728ull         // bf16 [T][F]           16777216
#define WS_WBF   150994944ull         // bf16 [G][F]           16777216
#define WS_HH    167772160ull         // f32  [T+1][H]         67117056
#define WS_PART  234889216ull         // f32  [T][256]          8388608

#define SENT 0x7F7F7F7Fu              // 3.39e38f — |h|<1 so never a real h value

static __device__ __forceinline__ float bf2f(u16 u) {
    union { u32 i; float f; } x; x.i = ((u32)u) << 16; return x.f;
}
static __device__ __forceinline__ u16 f2bf(float f) {
    union { float f; u32 u; } x; x.f = f;
    u32 r = (x.u + 0x7fffu + ((x.u >> 16) & 1u)) >> 16;
    return (u16)r;
}

// ---------- fp32 -> bf16 convert (4 elems/thread) ----------
__global__ void cvt4_kernel(const float* __restrict__ s, u16* __restrict__ d, int n4) {
    int i = blockIdx.x * 256 + threadIdx.x;
    if (i < n4) {
        float4 v = ((const float4*)s)[i];
        union { u16 h[4]; uint2 v2; } o;
        o.h[0] = f2bf(v.x); o.h[1] = f2bf(v.y); o.h[2] = f2bf(v.z); o.h[3] = f2bf(v.w);
        ((uint2*)d)[i] = o.v2;
    }
}

// ---------- x_gates GEMM: xg[t][g] = sum_f A[t][f]*W[g][f] + b_ih[g]+b_hh[g] ----------
__global__ __launch_bounds__(256) void gemm_xg_kernel(
    const u16* __restrict__ A,   // [T][F] bf16
    const u16* __restrict__ W,   // [G][F] bf16
    const float* __restrict__ b_ih, const float* __restrict__ b_hh,
    u16* __restrict__ xg)        // [T][G] bf16
{
    __shared__ u16 As[64][40];
    __shared__ u16 Ws[64][40];

    const int tb = blockIdx.y * 64;
    const int gb = blockIdx.x * 64;
    const int tid  = threadIdx.x;
    const int wave = tid >> 6;
    const int lane = tid & 63;
    const int m    = lane & 15;
    const int quad = lane >> 4;

    const int lrow = tid >> 2;
    const int lcol = (tid & 3) * 8;

    using frag  = __attribute__((ext_vector_type(8))) short;
    using f32x4 = __attribute__((ext_vector_type(4))) float;
    f32x4 acc[4] = {};

    for (int k0 = 0; k0 < F_; k0 += 32) {
        __syncthreads();
        *(uint4*)&As[lrow][lcol] = *(const uint4*)&A[(size_t)(tb + lrow) * F_ + k0 + lcol];
        *(uint4*)&Ws[lrow][lcol] = *(const uint4*)&W[(size_t)(gb + lrow) * F_ + k0 + lcol];
        __syncthreads();
        frag bfr = *(const frag*)&Ws[wave * 16 + m][quad * 8];
#pragma unroll
        for (int i = 0; i < 4; ++i) {
            frag afr = *(const frag*)&As[i * 16 + m][quad * 8];
            acc[i] = __builtin_amdgcn_mfma_f32_16x16x32_bf16(afr, bfr, acc[i], 0, 0, 0);
        }
    }
    const int g = gb + wave * 16 + m;
    const float bias = b_ih[g] + b_hh[g];
#pragma unroll
    for (int i = 0; i < 4; ++i)
#pragma unroll
        for (int r = 0; r < 4; ++r) {
            int t = tb + i * 16 + quad * 4 + r;
            xg[(size_t)t * G_ + g] = f2bf(acc[i][r] + bias);
        }
}

// ---------- persistent LSTM recurrence, sentinel-dataflow sync ----------
// 256 blocks x 512 threads (8 waves). Wave w of block b owns hidden unit uu=b*8+w.
// Sync protocol: hh[] is pre-filled with SENT; each h word is its own data+flag.
// Producers publish via relaxed agent atomic stores (write-through to LLC);
// consumers poll via relaxed agent u64 atomic loads (bypass stale L1/L2).
// No counter, no RMW contention, no threadfence/buffer_inv.
__global__ __launch_bounds__(512, 2) void lstm_rec_kernel(
    const float* __restrict__ Whh,   // [G][H] f32
    const u16*  __restrict__ xg,     // [T][G] bf16
    const float* __restrict__ Wout,  // [H]
    float* __restrict__ hh,          // [T+1][H]; slot 0 zeroed, rest = SENT
    float* __restrict__ part)        // [T][256]
{
    __shared__ float hs[H_];
    __shared__ float pl[8];

    const int b   = blockIdx.x;
    const int tid = threadIdx.x;
    const int w   = tid >> 6;
    const int l   = tid & 63;
    const int uu  = b * 8 + w;          // hidden unit (wave-uniform)

    // preload weights: wreg[r][kc*4+j] = Whh[2048*r + uu][4*l + 256*kc + j]
    float wreg[4][32];
#pragma unroll
    for (int r = 0; r < 4; ++r) {
        const float* wrow = &Whh[(size_t)(2048 * r + uu) * H_];
#pragma unroll
        for (int kc = 0; kc < 8; ++kc) {
            float4 v = *(const float4*)&wrow[4 * l + 256 * kc];
            wreg[r][kc * 4 + 0] = v.x; wreg[r][kc * 4 + 1] = v.y;
            wreg[r][kc * 4 + 2] = v.z; wreg[r][kc * 4 + 3] = v.w;
        }
    }
    const float wout = Wout[uu];
    float c = 0.f;

    // h_{-1} = 0 from slot 0 (plain load: written by prior memset on same stream)
    *(float4*)&hs[tid * 4] = *(const float4*)&hh[tid * 4];
    __syncthreads();

    for (int t = 0; t < T_; ++t) {
        // prefetch this step's x-gate contributions (lane 0 only uses them)
        float xgi = 0.f, xgf = 0.f, xgg = 0.f, xgo = 0.f;
        if (l == 0) {
            const u16* xr = &xg[(size_t)t * G_ + uu];
            xgi = bf2f(xr[0]); xgf = bf2f(xr[2048]);
            xgg = bf2f(xr[4096]); xgo = bf2f(xr[6144]);
        }

        float a0 = 0.f, a1 = 0.f, a2 = 0.f, a3 = 0.f;
#pragma unroll
        for (int kc = 0; kc < 8; ++kc) {
            float4 hv = *(const float4*)&hs[4 * l + 256 * kc];
            a0 = fmaf(wreg[0][kc*4+0], hv.x, a0); a0 = fmaf(wreg[0][kc*4+1], hv.y, a0);
            a0 = fmaf(wreg[0][kc*4+2], hv.z, a0); a0 = fmaf(wreg[0][kc*4+3], hv.w, a0);
            a1 = fmaf(wreg[1][kc*4+0], hv.x, a1); a1 = fmaf(wreg[1][kc*4+1], hv.y, a1);
            a1 = fmaf(wreg[1][kc*4+2], hv.z, a1); a1 = fmaf(wreg[1][kc*4+3], hv.w, a1);
            a2 = fmaf(wreg[2][kc*4+0], hv.x, a2); a2 = fmaf(wreg[2][kc*4+1], hv.y, a2);
            a2 = fmaf(wreg[2][kc*4+2], hv.z, a2); a2 = fmaf(wreg[2][kc*4+3], hv.w, a2);
            a3 = fmaf(wreg[3][kc*4+0], hv.x, a3); a3 = fmaf(wreg[3][kc*4+1], hv.y, a3);
            a3 = fmaf(wreg[3][kc*4+2], hv.z, a3); a3 = fmaf(wreg[3][kc*4+3], hv.w, a3);
        }
#pragma unroll
        for (int off = 32; off >= 1; off >>= 1) {
            a0 += __shfl_down(a0, off);
            a1 += __shfl_down(a1, off);
            a2 += __shfl_down(a2, off);
            a3 += __shfl_down(a3, off);
        }

        if (l == 0) {
            float gi = a0 + xgi, gf = a1 + xgf, gg = a2 + xgg, go = a3 + xgo;
            float i_ = 1.f / (1.f + __expf(-gi));
            float f_ = 1.f / (1.f + __expf(-gf));
            float g_ = tanhf(gg);
            float o_ = 1.f / (1.f + __expf(-go));
            c = fmaf(f_, c, i_ * g_);
            float hval = o_ * tanhf(c);
            // publish: data IS the flag (write-through, agent scope)
            __hip_atomic_store(&hh[(size_t)(t + 1) * H_ + uu], hval,
                               __ATOMIC_RELAXED, __HIP_MEMORY_SCOPE_AGENT);
            pl[w] = hval * wout;
        }
        __syncthreads();   // all waves done reading hs; pl[] complete

        if (tid == 0) {
            part[(size_t)t * 256 + b] = pl[0] + pl[1] + pl[2] + pl[3]
                                      + pl[4] + pl[5] + pl[6] + pl[7];
        }

        // poll h_{t+1}: thread tid owns floats [4*tid, 4*tid+4) as 2 u64 words
        {
            const u64* hp = (const u64*)&hh[(size_t)(t + 1) * H_] + tid * 2;
            u64 v0, v1;
            do {
                v0 = __hip_atomic_load(hp, __ATOMIC_RELAXED, __HIP_MEMORY_SCOPE_AGENT);
            } while ((u32)v0 == SENT || (u32)(v0 >> 32) == SENT);
            do {
                v1 = __hip_atomic_load(hp + 1, __ATOMIC_RELAXED, __HIP_MEMORY_SCOPE_AGENT);
            } while ((u32)v1 == SENT || (u32)(v1 >> 32) == SENT);
            union { u64 q[2]; float f[4]; } hx;
            hx.q[0] = v0; hx.q[1] = v1;
            *(float4*)&hs[tid * 4] = *(float4*)hx.f;
        }
        __syncthreads();
    }
}

// ---------- final: out[t] = b_out + sum_b part[t][b] ----------
__global__ __launch_bounds__(256) void out_reduce_kernel(
    const float* __restrict__ part, const float* __restrict__ b_out,
    float* __restrict__ out)
{
    int t = blockIdx.x * 4 + (threadIdx.x >> 6);
    int l = threadIdx.x & 63;
    const float* p = &part[(size_t)t * 256];
    float s = p[l] + p[l + 64] + p[l + 128] + p[l + 192];
#pragma unroll
    for (int off = 32; off >= 1; off >>= 1) s += __shfl_down(s, off);
    if (l == 0) out[t] = s + b_out[0];
}

extern "C" void kernel_launch(void* const* d_in, const int* in_sizes, int n_in,
                              void* d_out, int out_size, void* d_ws, size_t ws_size,
                              hipStream_t stream) {
    const float* input = (const float*)d_in[0];
    const float* W_ih  = (const float*)d_in[1];
    const float* W_hh  = (const float*)d_in[2];
    const float* b_ih  = (const float*)d_in[3];
    const float* b_hh  = (const float*)d_in[4];
    const float* W_out = (const float*)d_in[5];
    const float* b_out = (const float*)d_in[6];
    float* out = (float*)d_out;

    char* ws = (char*)d_ws;
    u16*   xg   = (u16*)(ws + WS_XG);
    u16*   Abf  = (u16*)(ws + WS_ABF);
    u16*   Wbf  = (u16*)(ws + WS_WBF);
    float* hh   = (float*)(ws + WS_HH);
    float* part = (float*)(ws + WS_PART);

    // fill hh with sentinel (0x7f bytes -> 0x7F7F7F7F), then zero slot 0 (h_{-1}=0)
    (void)hipMemsetAsync(hh, 0x7f, (size_t)(T_ + 1) * H_ * sizeof(float), stream);
    (void)hipMemsetAsync(hh, 0, H_ * sizeof(float), stream);

    const int n4 = (T_ * F_) / 4;
    cvt4_kernel<<<(n4 + 255) / 256, 256, 0, stream>>>(input, Abf, n4);
    cvt4_kernel<<<(G_ * F_ / 4 + 255) / 256, 256, 0, stream>>>(W_ih, Wbf, G_ * F_ / 4);

    gemm_xg_kernel<<<dim3(G_ / 64, T_ / 64), 256, 0, stream>>>(Abf, Wbf, b_ih, b_hh, xg);

    lstm_rec_kernel<<<256, 512, 0, stream>>>(W_hh, xg, W_out, hh, part);

    out_reduce_kernel<<<T_ / 4, 256, 0, stream>>>(part, b_out, out);
}